// Round 1
// baseline (1433.924 us; speedup 1.0000x reference)
//
#include <hip/hip_runtime.h>

typedef __attribute__((ext_vector_type(8))) short bf16x8;
typedef __attribute__((ext_vector_type(4))) short s16x4;
typedef __attribute__((ext_vector_type(4))) float f32x4;

#define MFMA16(a,b,c) __builtin_amdgcn_mfma_f32_16x16x32_bf16((a),(b),(c),0,0,0)

__device__ __forceinline__ unsigned short f2bf(float f) {
  unsigned int u = __float_as_uint(f);
  return (unsigned short)((u + 0x7fffu + ((u >> 16) & 1u)) >> 16);  // RNE
}

// C = A[32768,1024] @ W[1024,N], fp32 inputs converted to bf16 during staging.
// mode 0: C row-major [32768][N] bf16, scaled by `scale`.
// mode 2: C transposed per batch of 2048 rows: C[b][e][t] = (A@W)[b*2048+t][e].
__global__ __launch_bounds__(256) void proj_gemm(
    const float* __restrict__ A, const float* __restrict__ W,
    unsigned short* __restrict__ C, int N, int mode, float scale)
{
  __shared__ __align__(16) unsigned short As[128 * 40];  // [128 rows][32 k + 8 pad]
  __shared__ __align__(16) unsigned short Bs[128 * 40];  // [128 cols][32 k + 8 pad] (W^T)
  const int K = 1024;
  const int tid  = threadIdx.x;
  const int lane = tid & 63, w = tid >> 6;
  const int wr = w >> 1, wc = w & 1;
  const int lrow = lane & 15, lg = lane >> 4;
  f32x4 acc[4][4] = {};

  const float* Ablk = A + (size_t)blockIdx.x * 128 * K;
  const float* Wblk = W + blockIdx.y * 128;

  for (int kt = 0; kt < 32; ++kt) {
    __syncthreads();
    // stage A tile: 128x32 f32 -> bf16 LDS (coalesced float4 reads)
#pragma unroll
    for (int i = 0; i < 4; ++i) {
      int c = tid + 256 * i;               // 0..1023 float4-chunks
      int row = c >> 3, kq = c & 7;
      float4 v = *(const float4*)(Ablk + (size_t)row * K + kt * 32 + kq * 4);
      unsigned short* d = &As[row * 40 + kq * 4];
      d[0] = f2bf(v.x); d[1] = f2bf(v.y); d[2] = f2bf(v.z); d[3] = f2bf(v.w);
    }
    // stage W tile transposed: W[32k][128n] -> Bs[n][k]
#pragma unroll
    for (int i = 0; i < 4; ++i) {
      int c = tid + 256 * i;
      int k = c >> 5, n4 = c & 31;
      float4 v = *(const float4*)(Wblk + (size_t)(kt * 32 + k) * N + n4 * 4);
      Bs[(n4 * 4 + 0) * 40 + k] = f2bf(v.x);
      Bs[(n4 * 4 + 1) * 40 + k] = f2bf(v.y);
      Bs[(n4 * 4 + 2) * 40 + k] = f2bf(v.z);
      Bs[(n4 * 4 + 3) * 40 + k] = f2bf(v.w);
    }
    __syncthreads();
    bf16x8 af[4], bfr[4];
#pragma unroll
    for (int i = 0; i < 4; ++i)
      af[i] = *(const bf16x8*)&As[(wr * 64 + i * 16 + lrow) * 40 + lg * 8];
#pragma unroll
    for (int j = 0; j < 4; ++j)
      bfr[j] = *(const bf16x8*)&Bs[(wc * 64 + j * 16 + lrow) * 40 + lg * 8];
#pragma unroll
    for (int i = 0; i < 4; ++i)
#pragma unroll
      for (int j = 0; j < 4; ++j)
        acc[i][j] = MFMA16(af[i], bfr[j], acc[i][j]);
  }

  const int orow0 = blockIdx.x * 128 + wr * 64;
  const int ocol0 = blockIdx.y * 128 + wc * 64;
  if (mode == 0) {
#pragma unroll
    for (int i = 0; i < 4; ++i)
#pragma unroll
      for (int j = 0; j < 4; ++j) {
        int col = ocol0 + j * 16 + lrow;
#pragma unroll
        for (int r = 0; r < 4; ++r) {
          int row = orow0 + i * 16 + lg * 4 + r;
          C[(size_t)row * N + col] = f2bf(acc[i][j][r] * scale);
        }
      }
  } else {
#pragma unroll
    for (int i = 0; i < 4; ++i) {
      int m0 = orow0 + i * 16 + lg * 4;       // 4-row group never crosses batch bdry
      int bb = m0 >> 11, t = m0 & 2047;
#pragma unroll
      for (int j = 0; j < 4; ++j) {
        int e = ocol0 + j * 16 + lrow;
        s16x4 pk;
#pragma unroll
        for (int r = 0; r < 4; ++r) pk[r] = (short)f2bf(acc[i][j][r]);
        *(s16x4*)(C + (size_t)bb * 2097152 + (size_t)e * 2048 + t) = pk;
      }
    }
  }
}

// Flash attention: block = 512 thr (8 waves), QB=64 q-rows, KT=64.
// Wave w: computes S sub-tiles (row i = w&3, cols 2*(w>>2)+{0,1}), owns output
// cols [128w, 128w+128). Q pre-scaled by 1/sqrt(1024) in ws.
__global__ __launch_bounds__(512) void attn_kernel(
    const unsigned short* __restrict__ Q,   // [16][2048][256] bf16 (scaled)
    const unsigned short* __restrict__ Kk,  // [16][2048][256] bf16
    const unsigned short* __restrict__ Vt,  // [16][1024][2048] bf16 (transposed)
    const float* __restrict__ X, float* __restrict__ Out)
{
  __shared__ __align__(16) unsigned short Ks[64 * 264];  // [64][256+8]
  __shared__ __align__(16) float Ss[64 * 68];            // [64][64+4]
  __shared__ __align__(16) unsigned short Ps[64 * 72];   // [64][64+8]
  __shared__ float m_s[64], l_s[64], al_s[64];

  const int b  = blockIdx.y;
  const int q0 = blockIdx.x * 64;
  const int tid  = threadIdx.x;
  const int lane = tid & 63, w = tid >> 6;
  const int lrow = lane & 15, lg = lane >> 4;
  const int si = w & 3, sj0 = (w >> 2) * 2;

  if (tid < 64) { m_s[tid] = -3.0e38f; l_s[tid] = 0.0f; }

  // Q fragments in registers: rows si*16+lrow, all 8 k-steps (k = ks*32+lg*8)
  bf16x8 qf[8];
  const unsigned short* qb = Q + ((size_t)b * 2048 + q0 + si * 16 + lrow) * 256;
#pragma unroll
  for (int ks = 0; ks < 8; ++ks) qf[ks] = *(const bf16x8*)(qb + ks * 32 + lg * 8);

  const unsigned short* kb = Kk + (size_t)b * 2048 * 256;
  const unsigned short* vb = Vt + (size_t)b * 1024 * 2048;

  f32x4 acc[4][8] = {};  // rows 16i+(lg*4+r), cols 128w+16n+lrow

  for (int t0 = 0; t0 < 2048; t0 += 64) {
    // stage K tile (bf16 global -> padded LDS)
#pragma unroll
    for (int i = 0; i < 4; ++i) {
      int c = tid + 512 * i;                 // 2048 8-elem chunks
      int row = c >> 5, cc = c & 31;
      *(bf16x8*)&Ks[row * 264 + cc * 8] =
          *(const bf16x8*)(kb + (size_t)(t0 + row) * 256 + cc * 8);
    }
    __syncthreads();
    // QK^T -> S tile in LDS (f32, verified D-layout)
    {
      f32x4 s0v = {}, s1v = {};
#pragma unroll
      for (int ks = 0; ks < 8; ++ks) {
        bf16x8 k0 = *(const bf16x8*)&Ks[(sj0 * 16 + lrow) * 264 + ks * 32 + lg * 8];
        bf16x8 k1 = *(const bf16x8*)&Ks[(sj0 * 16 + 16 + lrow) * 264 + ks * 32 + lg * 8];
        s0v = MFMA16(qf[ks], k0, s0v);
        s1v = MFMA16(qf[ks], k1, s1v);
      }
#pragma unroll
      for (int r = 0; r < 4; ++r) {
        Ss[(si * 16 + lg * 4 + r) * 68 + sj0 * 16 + lrow]      = s0v[r];
        Ss[(si * 16 + lg * 4 + r) * 68 + sj0 * 16 + 16 + lrow] = s1v[r];
      }
    }
    __syncthreads();
    // online softmax: 8 threads per row, butterfly over 8 lanes
    {
      const int row = tid >> 3, sl = tid & 7;
      float4 a0 = *(const float4*)&Ss[row * 68 + sl * 8];
      float4 a1 = *(const float4*)&Ss[row * 68 + sl * 8 + 4];
      float sv[8] = {a0.x, a0.y, a0.z, a0.w, a1.x, a1.y, a1.z, a1.w};
      float mx = sv[0];
#pragma unroll
      for (int j = 1; j < 8; ++j) mx = fmaxf(mx, sv[j]);
      mx = fmaxf(mx, __shfl_xor(mx, 1));
      mx = fmaxf(mx, __shfl_xor(mx, 2));
      mx = fmaxf(mx, __shfl_xor(mx, 4));
      float mo = m_s[row];              // wave-lockstep: read before sl==0 writes
      float mn = fmaxf(mo, mx);
      float p[8], sum = 0.f;
#pragma unroll
      for (int j = 0; j < 8; ++j) { p[j] = __expf(sv[j] - mn); sum += p[j]; }
      sum += __shfl_xor(sum, 1);
      sum += __shfl_xor(sum, 2);
      sum += __shfl_xor(sum, 4);
      if (sl == 0) {
        float al = __expf(mo - mn);
        al_s[row] = al;
        m_s[row]  = mn;
        l_s[row]  = l_s[row] * al + sum;
      }
      bf16x8 pk;
#pragma unroll
      for (int j = 0; j < 8; ++j) pk[j] = (short)f2bf(p[j]);
      *(bf16x8*)&Ps[row * 72 + sl * 8] = pk;
    }
    __syncthreads();
    // rescale accumulator + P @ V (V fragments direct from global Vt)
    {
#pragma unroll
      for (int i = 0; i < 4; ++i) {
        f32x4 al4;
#pragma unroll
        for (int r = 0; r < 4; ++r) al4[r] = al_s[i * 16 + lg * 4 + r];
#pragma unroll
        for (int n = 0; n < 8; ++n) acc[i][n] *= al4;
      }
#pragma unroll
      for (int kk = 0; kk < 2; ++kk) {
        bf16x8 pf[4];
#pragma unroll
        for (int i = 0; i < 4; ++i)
          pf[i] = *(const bf16x8*)&Ps[(i * 16 + lrow) * 72 + kk * 32 + lg * 8];
#pragma unroll
        for (int n = 0; n < 8; ++n) {
          bf16x8 vf = *(const bf16x8*)(vb + (size_t)(w * 128 + n * 16 + lrow) * 2048
                                          + t0 + kk * 32 + lg * 8);
#pragma unroll
          for (int i = 0; i < 4; ++i)
            acc[i][n] = MFMA16(pf[i], vf, acc[i][n]);
        }
      }
    }
  }

  // epilogue: out = acc / l + x
#pragma unroll
  for (int i = 0; i < 4; ++i) {
#pragma unroll
    for (int r = 0; r < 4; ++r) {
      int row = i * 16 + lg * 4 + r;
      float inv = 1.0f / l_s[row];
      const float* xr = X + ((size_t)b * 2048 + q0 + row) * 1024;
      float* orp = Out + ((size_t)b * 2048 + q0 + row) * 1024;
#pragma unroll
      for (int n = 0; n < 8; ++n) {
        int col = w * 128 + n * 16 + lrow;
        orp[col] = acc[i][n][r] * inv + xr[col];
      }
    }
  }
}

extern "C" void kernel_launch(void* const* d_in, const int* in_sizes, int n_in,
                              void* d_out, int out_size, void* d_ws, size_t ws_size,
                              hipStream_t stream) {
  (void)in_sizes; (void)n_in; (void)out_size; (void)ws_size;
  const float* x  = (const float*)d_in[0];
  const float* y  = (const float*)d_in[1];
  const float* Wq = (const float*)d_in[2];
  const float* Wk = (const float*)d_in[3];
  const float* Wv = (const float*)d_in[4];
  float* out = (float*)d_out;

  // ws layout (bf16): q[16][2048][256] | k[16][2048][256] | vt[16][1024][2048]
  unsigned short* qws  = (unsigned short*)d_ws;
  unsigned short* kws  = qws + (size_t)16 * 2048 * 256;
  unsigned short* vtws = kws + (size_t)16 * 2048 * 256;

  // q scaled by 1/sqrt(OUT_DIM)=1/32 (folded into projection epilogue)
  proj_gemm<<<dim3(256, 2), dim3(256), 0, stream>>>(x, Wq, qws, 256, 0, 0.03125f);
  proj_gemm<<<dim3(256, 2), dim3(256), 0, stream>>>(y, Wk, kws, 256, 0, 1.0f);
  proj_gemm<<<dim3(256, 8), dim3(256), 0, stream>>>(y, Wv, vtws, 1024, 2, 1.0f);
  attn_kernel<<<dim3(32, 16), dim3(512), 0, stream>>>(qws, kws, vtws, x, out);
}

// Round 2
// 634.087 us; speedup vs baseline: 2.2614x; 2.2614x over previous
//
#include <hip/hip_runtime.h>

typedef __attribute__((ext_vector_type(8))) short bf16x8;
typedef __attribute__((ext_vector_type(4))) short s16x4;
typedef __attribute__((ext_vector_type(4))) float f32x4;

#define MFMA16(a,b,c) __builtin_amdgcn_mfma_f32_16x16x32_bf16((a),(b),(c),0,0,0)

__device__ __forceinline__ unsigned short f2bf(float f) {
  unsigned int u = __float_as_uint(f);
  return (unsigned short)((u + 0x7fffu + ((u >> 16) & 1u)) >> 16);  // RNE
}

__device__ __forceinline__ void gload16(const void* g, void* l) {
  __builtin_amdgcn_global_load_lds((const __attribute__((address_space(1))) void*)g,
                                   (__attribute__((address_space(3))) void*)l, 16, 0, 0);
}

// ---- f32 -> bf16 bulk convert (8 elems/thread/step) ----
__global__ __launch_bounds__(256) void cvt_bf16(const float* __restrict__ in,
                                                unsigned short* __restrict__ out, int n8) {
  for (int i = blockIdx.x * 256 + threadIdx.x; i < n8; i += gridDim.x * 256) {
    float4 a = ((const float4*)in)[2 * i];
    float4 b = ((const float4*)in)[2 * i + 1];
    s16x4 p0, p1;
    p0[0] = f2bf(a.x); p0[1] = f2bf(a.y); p0[2] = f2bf(a.z); p0[3] = f2bf(a.w);
    p1[0] = f2bf(b.x); p1[1] = f2bf(b.y); p1[2] = f2bf(b.z); p1[3] = f2bf(b.w);
    ((s16x4*)out)[2 * i] = p0;
    ((s16x4*)out)[2 * i + 1] = p1;
  }
}

// ---- W[K][N] f32 -> Wt[N][K] bf16 (32x32 LDS tile transpose) ----
__global__ __launch_bounds__(256) void tcvt(const float* __restrict__ W,
                                            unsigned short* __restrict__ Wt, int K, int N) {
  __shared__ float t[32][33];
  const int n0 = blockIdx.x * 32, k0 = blockIdx.y * 32;
  const int c = threadIdx.x & 31, r8 = threadIdx.x >> 5;
#pragma unroll
  for (int p = 0; p < 4; ++p) {
    int r = r8 + p * 8;
    t[r][c] = W[(size_t)(k0 + r) * N + n0 + c];
  }
  __syncthreads();
#pragma unroll
  for (int p = 0; p < 4; ++p) {
    int r = r8 + p * 8;
    Wt[(size_t)(n0 + r) * K + k0 + c] = f2bf(t[c][r]);
  }
}

// ---- bf16 GEMM: C = A[M,1024] @ Bt[N,1024]^T; m97-style gload_lds + dbuf ----
// mode 0: C row-major [M][N] bf16 scaled.
// mode 2: packed V tiles: C[b][e/16][t/32][e%16][t%32], b = m>>11, t = m&2047, e = n.
__global__ __launch_bounds__(256) void proj_gemm(
    const unsigned short* __restrict__ A, const unsigned short* __restrict__ Bt,
    unsigned short* __restrict__ C, int N, int mode, float scale)
{
  __shared__ __align__(16) unsigned short As[2][4096];  // [128][32] linear
  __shared__ __align__(16) unsigned short Bs[2][4096];
  const int tid = threadIdx.x, lane = tid & 63, w = tid >> 6;
  const int wr = w >> 1, wc = w & 1;
  const int lrow = lane & 15, lg = lane >> 4;
  const size_t bm = (size_t)blockIdx.x * 128;
  const size_t bn = (size_t)blockIdx.y * 128;
  const int rl = lane >> 2, cq = lane & 3;  // staging: 16 rows x 4 16B-chunks = 1KB/instr

  auto stage = [&](int kt, int buf) {
#pragma unroll
    for (int u = 0; u < 2; ++u) {
      int row = w * 32 + u * 16 + rl;
      gload16(A  + (bm + row) * 1024 + kt * 32 + cq * 8, &As[buf][(w * 32 + u * 16) * 32]);
      gload16(Bt + (bn + row) * 1024 + kt * 32 + cq * 8, &Bs[buf][(w * 32 + u * 16) * 32]);
    }
  };

  f32x4 acc[4][4] = {};
  stage(0, 0);
  __syncthreads();

  for (int kt = 0; kt < 32; ++kt) {
    const int cur = kt & 1;
    if (kt + 1 < 32) stage(kt + 1, cur ^ 1);
    bf16x8 af[4], bfr[4];
#pragma unroll
    for (int i = 0; i < 4; ++i)
      af[i] = *(const bf16x8*)&As[cur][(wr * 64 + i * 16 + lrow) * 32 + lg * 8];
#pragma unroll
    for (int j = 0; j < 4; ++j)
      bfr[j] = *(const bf16x8*)&Bs[cur][(wc * 64 + j * 16 + lrow) * 32 + lg * 8];
    __builtin_amdgcn_s_setprio(1);
#pragma unroll
    for (int i = 0; i < 4; ++i)
#pragma unroll
      for (int j = 0; j < 4; ++j)
        acc[i][j] = MFMA16(af[i], bfr[j], acc[i][j]);
    __builtin_amdgcn_s_setprio(0);
    __syncthreads();   // drains gload_lds (vmcnt) + guards buffer swap
  }

  const int orow0 = blockIdx.x * 128 + wr * 64;
  const int ocol0 = blockIdx.y * 128 + wc * 64;
  if (mode == 0) {
#pragma unroll
    for (int i = 0; i < 4; ++i)
#pragma unroll
      for (int j = 0; j < 4; ++j) {
        int col = ocol0 + j * 16 + lrow;
#pragma unroll
        for (int r = 0; r < 4; ++r) {
          int row = orow0 + i * 16 + lg * 4 + r;
          C[(size_t)row * N + col] = f2bf(acc[i][j][r] * scale);
        }
      }
  } else {
#pragma unroll
    for (int i = 0; i < 4; ++i) {
      int m0 = orow0 + i * 16 + lg * 4;   // 4 consecutive t, same 32-group
      int bb = m0 >> 11, t = m0 & 2047;
      int tg = t >> 5, tin = t & 31;
#pragma unroll
      for (int j = 0; j < 4; ++j) {
        int e = ocol0 + j * 16 + lrow;
        int eg = e >> 4;                  // e%16 == lrow
        s16x4 pk;
#pragma unroll
        for (int r = 0; r < 4; ++r) pk[r] = (short)f2bf(acc[i][j][r]);
        *(s16x4*)(C + (size_t)bb * 2097152 + ((size_t)eg * 64 + tg) * 512 + lrow * 32 + tin) = pk;
      }
    }
  }
}

// ---- Flash attention: 512 thr, QB=64, KT=64, XCD-pinned batches, packed V ----
__global__ __launch_bounds__(512) void attn_kernel(
    const unsigned short* __restrict__ Q,   // [16][2048][256] bf16 (pre-scaled)
    const unsigned short* __restrict__ Kk,  // [16][2048][256] bf16
    const unsigned short* __restrict__ Vp,  // packed [16][64][64][16][32] bf16
    const float* __restrict__ X, float* __restrict__ Out)
{
  __shared__ __align__(16) unsigned short Ks[2][64 * 256];  // linear [64][256], XOR-swizzled content
  __shared__ __align__(16) float Ss[64 * 68];
  __shared__ __align__(16) unsigned short Ps[64 * 72];
  __shared__ float m_s[64], l_s[64], al_s[64];

  // XCD swizzle: batch b pinned to XCD b/2 (assumes bid%8 round-robin dispatch).
  const int bid = blockIdx.x;
  const int xcd = bid & 7, slot = bid >> 3;
  const int b = xcd * 2 + (slot >> 5);
  const int q0 = (slot & 31) * 64;

  const int tid = threadIdx.x, lane = tid & 63, w = tid >> 6;
  const int lrow = lane & 15, lg = lane >> 4;
  const int si = w & 3, sj0 = (w >> 2) * 2;

  if (tid < 64) { m_s[tid] = -3.0e38f; l_s[tid] = 0.f; }

  bf16x8 qf[8];
  const unsigned short* qb = Q + ((size_t)b * 2048 + q0 + si * 16 + lrow) * 256;
#pragma unroll
  for (int ks = 0; ks < 8; ++ks) qf[ks] = *(const bf16x8*)(qb + ks * 32 + lg * 8);

  const unsigned short* kb = Kk + (size_t)b * 2048 * 256;
  const unsigned short* vb = Vp + (size_t)b * 2097152;

  // K staging: gload_lds writes LINEAR (base + lane*16B); pre-swizzle the GLOBAL
  // source so the reader's byte^((row&7)<<4) XOR sees the right data (rule #21).
  const int srl = lane >> 5, scc = (lane & 31) * 16;
  auto stageK = [&](int tile, int buf) {
#pragma unroll
    for (int is = 0; is < 4; ++is) {
      int row = w * 8 + is * 2 + srl;
      int cb = scc ^ ((row & 7) << 4);
      gload16((const char*)kb + (size_t)(tile * 64 + row) * 512 + cb,
              (char*)&Ks[buf][0] + (w * 8 + is * 2) * 512);
    }
  };

  f32x4 acc[4][8] = {};  // rows 16i+(lg*4+r), cols 128w+16n+lrow

  stageK(0, 0);
  __syncthreads();

  const int r0 = sj0 * 16 + lrow;
  const int rx = (r0 & 7) << 4;   // same for r0 and r0+16

  for (int it = 0; it < 32; ++it) {
    const int cur = it & 1;
    // ---- P1: QK^T -> Ss ----
    {
      f32x4 s0v = {}, s1v = {};
      const char* kbase = (const char*)&Ks[cur][0];
      __builtin_amdgcn_s_setprio(1);
#pragma unroll
      for (int ks = 0; ks < 8; ++ks) {
        bf16x8 k0 = *(const bf16x8*)(kbase + r0 * 512 + ((ks * 64 + lg * 16) ^ rx));
        bf16x8 k1 = *(const bf16x8*)(kbase + (r0 + 16) * 512 + ((ks * 64 + lg * 16) ^ rx));
        s0v = MFMA16(qf[ks], k0, s0v);
        s1v = MFMA16(qf[ks], k1, s1v);
      }
      __builtin_amdgcn_s_setprio(0);
#pragma unroll
      for (int r = 0; r < 4; ++r) {
        Ss[(si * 16 + lg * 4 + r) * 68 + sj0 * 16 + lrow]      = s0v[r];
        Ss[(si * 16 + lg * 4 + r) * 68 + sj0 * 16 + 16 + lrow] = s1v[r];
      }
    }
    __syncthreads();
    // ---- P2: online softmax (8 threads/row) ----
    {
      const int row = tid >> 3, sl = tid & 7;
      float4 a0 = *(const float4*)&Ss[row * 68 + sl * 8];
      float4 a1 = *(const float4*)&Ss[row * 68 + sl * 8 + 4];
      float sv[8] = {a0.x, a0.y, a0.z, a0.w, a1.x, a1.y, a1.z, a1.w};
      float mx = sv[0];
#pragma unroll
      for (int j = 1; j < 8; ++j) mx = fmaxf(mx, sv[j]);
      mx = fmaxf(mx, __shfl_xor(mx, 1));
      mx = fmaxf(mx, __shfl_xor(mx, 2));
      mx = fmaxf(mx, __shfl_xor(mx, 4));
      float mo = m_s[row];            // wave-lockstep: read precedes sl==0 write
      float mn = fmaxf(mo, mx);
      float p[8], sum = 0.f;
#pragma unroll
      for (int j = 0; j < 8; ++j) { p[j] = __expf(sv[j] - mn); sum += p[j]; }
      sum += __shfl_xor(sum, 1);
      sum += __shfl_xor(sum, 2);
      sum += __shfl_xor(sum, 4);
      if (sl == 0) {
        float al = __expf(mo - mn);
        al_s[row] = al;
        m_s[row]  = mn;
        l_s[row]  = l_s[row] * al + sum;
      }
      bf16x8 pk;
#pragma unroll
      for (int j = 0; j < 8; ++j) pk[j] = (short)f2bf(p[j]);
      *(bf16x8*)&Ps[row * 72 + sl * 8] = pk;
    }
    __syncthreads();
    // ---- P3: prefetch next K tile, rescale, P@V ----
    if (it + 1 < 32) stageK(it + 1, cur ^ 1);
    {
#pragma unroll
      for (int i = 0; i < 4; ++i) {
        f32x4 al4;
#pragma unroll
        for (int r = 0; r < 4; ++r) al4[r] = al_s[i * 16 + lg * 4 + r];
#pragma unroll
        for (int n = 0; n < 8; ++n) acc[i][n] *= al4;
      }
#pragma unroll
      for (int kk = 0; kk < 2; ++kk) {
        bf16x8 pf[4];
#pragma unroll
        for (int i = 0; i < 4; ++i)
          pf[i] = *(const bf16x8*)&Ps[(i * 16 + lrow) * 72 + kk * 32 + lg * 8];
        __builtin_amdgcn_s_setprio(1);
#pragma unroll
        for (int n = 0; n < 8; ++n) {
          // packed tile: wave reads one contiguous 1KB line
          bf16x8 vf = *(const bf16x8*)(vb + ((size_t)(w * 8 + n) * 64 + (it * 2 + kk)) * 512
                                          + lrow * 32 + lg * 8);
#pragma unroll
          for (int i = 0; i < 4; ++i)
            acc[i][n] = MFMA16(pf[i], vf, acc[i][n]);
        }
        __builtin_amdgcn_s_setprio(0);
      }
    }
    __syncthreads();   // drains K prefetch; guards Ss/Ps reuse
  }

  // ---- epilogue: out = acc / l + x ----
#pragma unroll
  for (int i = 0; i < 4; ++i) {
#pragma unroll
    for (int r = 0; r < 4; ++r) {
      int row = i * 16 + lg * 4 + r;
      float inv = 1.0f / l_s[row];
      const float* xr = X + ((size_t)b * 2048 + q0 + row) * 1024;
      float* orp = Out + ((size_t)b * 2048 + q0 + row) * 1024;
#pragma unroll
      for (int n = 0; n < 8; ++n) {
        int col = w * 128 + n * 16 + lrow;
        orp[col] = acc[i][n][r] * inv + xr[col];
      }
    }
  }
}

extern "C" void kernel_launch(void* const* d_in, const int* in_sizes, int n_in,
                              void* d_out, int out_size, void* d_ws, size_t ws_size,
                              hipStream_t stream) {
  (void)in_sizes; (void)n_in; (void)out_size; (void)ws_size;
  const float* x  = (const float*)d_in[0];
  const float* y  = (const float*)d_in[1];
  const float* Wq = (const float*)d_in[2];
  const float* Wk = (const float*)d_in[3];
  const float* Wv = (const float*)d_in[4];
  float* out = (float*)d_out;

  // bf16 copies of x,y live in d_out (exactly 2 x 64MB; overwritten by attn at the end)
  unsigned short* xb = (unsigned short*)d_out;
  unsigned short* yb = xb + (size_t)16 * 2048 * 1024;

  // ws (bf16): Wqt | Wkt | Wvt | q | k | Vp
  unsigned short* Wqt = (unsigned short*)d_ws;
  unsigned short* Wkt = Wqt + (size_t)256 * 1024;
  unsigned short* Wvt = Wkt + (size_t)256 * 1024;
  unsigned short* qws = Wvt + (size_t)1024 * 1024;
  unsigned short* kws = qws + (size_t)16 * 2048 * 256;
  unsigned short* vpw = kws + (size_t)16 * 2048 * 256;

  const int n8 = (16 * 2048 * 1024) / 8;
  cvt_bf16<<<2048, 256, 0, stream>>>(x, xb, n8);
  cvt_bf16<<<2048, 256, 0, stream>>>(y, yb, n8);
  tcvt<<<dim3(8, 32),  256, 0, stream>>>(Wq, Wqt, 1024, 256);
  tcvt<<<dim3(8, 32),  256, 0, stream>>>(Wk, Wkt, 1024, 256);
  tcvt<<<dim3(32, 32), 256, 0, stream>>>(Wv, Wvt, 1024, 1024);

  // q scaled by 1/sqrt(OUT_DIM) = 1/32
  proj_gemm<<<dim3(256, 2), 256, 0, stream>>>(xb, Wqt, qws, 256, 0, 0.03125f);
  proj_gemm<<<dim3(256, 2), 256, 0, stream>>>(yb, Wkt, kws, 256, 0, 1.0f);
  proj_gemm<<<dim3(256, 8), 256, 0, stream>>>(yb, Wvt, vpw, 1024, 2, 1.0f);

  attn_kernel<<<512, 512, 0, stream>>>(qws, kws, vpw, x, out);
}